// Round 11
// baseline (59.227 us; speedup 1.0000x reference)
//
#include <hip/hip_runtime.h>
#include <hip/hip_bf16.h>

// CrossAttentionOutLayer: out[b,i,j] = (1/H) * sum_c Q'[b,i,c] * K[b,j,c]
//   Q' = SCALE*(rna@Wq.T + bq) + rel_bias   (c = h*DK+d == flat rel_bias idx)
//   K  = prot@Wk.T + bk
// B=8 N=1024 M=1024 DIM2=1280 KIN=1344 H=8 DK=64 HDK=512 SCALE=0.125
//
// R11: m201-style interleaved-phase schedule for proj (T3+T4). Five 2-phase
// variants all capped at ~440 TF (m233: 2-phase = ~70% structural stall).
// New geometry: BM=256 x BN=128, 256 blocks (1/CU), 8 waves (2/SIMD, m201's
// occupancy), 96KB dbuf LDS. Per K-step: 2 phases, each {vmcnt(6) counted ->
// cvt+6 ds_write (tile t+1, parity p^1) || issue 6 asm loads (t+2) || 8
// ds_read (tile t, parity p) -> BAR -> lgkm(0) -> setprio -> 16 MFMA ->
// setprio -> BAR}. 12 loads stay in flight across barriers (T4: never
// drain). Swizzle/addressing/C-layout carried from R10 (proven).

typedef __bf16 bf16x8 __attribute__((ext_vector_type(8)));
typedef __bf16 bf16x4 __attribute__((ext_vector_type(4)));
typedef float f32x4 __attribute__((ext_vector_type(4)));

__device__ inline bf16x4 cvt4(const f32x4 a) {
    bf16x4 r;
    r[0] = (__bf16)a[0]; r[1] = (__bf16)a[1];
    r[2] = (__bf16)a[2]; r[3] = (__bf16)a[3];
    return r;
}

// unsinkable 16B global load; dst EARLY-CLOBBER (never aliases addr regs).
// NO implicit wait — caller must s_waitcnt vmcnt before reading dst.
__device__ inline void gload4(f32x4& dst, const float* p) {
    asm volatile("global_load_dwordx4 %0, %1, off"
                 : "=&v"(dst) : "v"(p) : "memory");
}

#define SCHB  __builtin_amdgcn_sched_barrier(0)
#define BARR  __builtin_amdgcn_s_barrier()
#define LGKM0 asm volatile("s_waitcnt lgkmcnt(0)" ::: "memory")
#define WAITV(n_) asm volatile("s_waitcnt vmcnt(" #n_ ")" ::: "memory")

// ---------------------------------------------------------------------------
// Fused Q+K projection. Tile 256x128, BK=64, 8 waves (4Mx2N) of 64x64 each.
// bf16 double-buffered LDS (96KB -> 1 block/CU). grid 256, XCD swizzle.
// ---------------------------------------------------------------------------
__global__ __launch_bounds__(512, 2)
void proj_all(const float* __restrict__ rna,  const float* __restrict__ prot,
              const float* __restrict__ Wq,   const float* __restrict__ bq,
              const float* __restrict__ Wk,   const float* __restrict__ bk,
              const float* __restrict__ rb,
              __bf16* __restrict__ qout, __bf16* __restrict__ kout)
{
    __shared__ __bf16 AS[2][256 * 64];   // 2 x 32 KB
    __shared__ __bf16 WS[2][128 * 64];   // 2 x 16 KB

    const int bid = blockIdx.x;
    const int wg  = (bid & 7) * 32 + (bid >> 3);   // bijective XCD swizzle (256%8==0)
    const bool isQ = wg < 128;
    const int lwg  = isQ ? wg : wg - 128;
    const int brow = (lwg >> 2) * 256;   // 32 row tiles
    const int bcol = (lwg & 3) * 128;    // 4 col tiles

    const float* A    = isQ ? rna : prot;
    const float* W    = isQ ? Wq  : Wk;
    const float* bias = isQ ? bq  : bk;
    __bf16*      out  = isQ ? qout : kout;
    const int    K    = isQ ? 1280 : 1344;
    const int    nt   = K >> 6;          // 20 (Q) or 21 (K) steps

    const int tid  = threadIdx.x;
    const int lane = tid & 63;
    const int wid  = tid >> 6;           // 0..7
    const int wr   = wid >> 1;           // 0..3 -> 64-row strip
    const int wc   = wid & 1;            // 0..1 -> 64-col strip
    const int fr   = lane & 15;
    const int q4   = lane >> 4;

    // staging: A inst i (0..7): row rlocA+4i (wave rows [wid*32,+32));
    //          W inst j (0..3): row rlocW+4j (wave rows [wid*16,+16)); col fr*4.
    const int rlocA = wid * 32 + q4;
    const int rlocW = wid * 16 + q4;
    const float* aGlob = A + (size_t)(brow + rlocA) * K + fr * 4;
    const float* wGlob = W + (size_t)(bcol + rlocW) * K + fr * 4;
    // LDS write: mask3(row)=((row&3)<<1)|((row>>2)&1); row&3=q4, (row>>2)&1=inst&1
    const int lbA = rlocA * 128 + (((fr >> 1) ^ (q4 << 1)) << 4) + (lane & 1) * 8;
    const int lbW = rlocW * 128 + (((fr >> 1) ^ (q4 << 1)) << 4) + (lane & 1) * 8;
    // fragment-read swizzle (frag row&7 = fr&7)
    const int rmask = ((fr & 3) << 1) | ((fr >> 2) & 1);

    f32x4 acc[4][4] = {};
    f32x4 av[8], wv[4];                  // single reg set; FIFO discipline

#define ISS_A(i_, k0) gload4(av[i_], aGlob + (size_t)((i_) * 4) * K + (k0))
#define ISS_W(j_, k0) gload4(wv[j_], wGlob + (size_t)((j_) * 4) * K + (k0))
#define WR_A(i_, p_) *(bf16x4*)((char*)AS[p_] + ((lbA ^ (((i_) & 1) << 4)) + (i_) * 512)) = cvt4(av[i_])
#define WR_W(j_, p_) *(bf16x4*)((char*)WS[p_] + ((lbW ^ (((j_) & 1) << 4)) + (j_) * 512)) = cvt4(wv[j_])
#define RD_A(m_, kk_, p_) (*(const bf16x8*)((const char*)AS[p_] + (wr * 64 + (m_) * 16 + fr) * 128 + ((((kk_) * 4 + q4) ^ rmask) << 4)))
#define RD_W(n_, kk_, p_) (*(const bf16x8*)((const char*)WS[p_] + (wc * 64 + (n_) * 16 + fr) * 128 + ((((kk_) * 4 + q4) ^ rmask) << 4)))
#define MM(m_, n_, A_, B_) acc[m_][n_] = __builtin_amdgcn_mfma_f32_16x16x32_bf16(A_, B_, acc[m_][n_], 0, 0, 0)

// STEP(t,p): read tile t from buf[p]; write tile t+1 to buf[p^1]; issue t+2.
// FIFO at phase-A entry (steady): 12 loads of t+1 [A0..A7,W0..W3].
// phase A: WAITV(6) retires A0-5; write them; issue A0-5(t+2); MFMA kk0.
// phase B: WAITV(6) (tail: 0) retires A6,7,W0-3; write; issue rest; MFMA kk1.
#define STEP(t, p) do {                                                    \
    const int k2_ = ((t) + 2) * 64;                                        \
    bf16x8 af0, af1, af2, af3, bw0, bw1, bw2, bw3;                         \
    /* ---------------- phase A (kk=0) ---------------- */                 \
    if ((t) + 1 < nt) {                                                    \
        WAITV(6);                                                          \
        SCHB;                                                              \
        WR_A(0, (p) ^ 1); WR_A(1, (p) ^ 1); WR_A(2, (p) ^ 1);              \
        WR_A(3, (p) ^ 1); WR_A(4, (p) ^ 1); WR_A(5, (p) ^ 1);              \
    }                                                                      \
    if ((t) + 2 < nt) {                                                    \
        ISS_A(0, k2_); ISS_A(1, k2_); ISS_A(2, k2_);                       \
        ISS_A(3, k2_); ISS_A(4, k2_); ISS_A(5, k2_);                       \
    }                                                                      \
    af0 = RD_A(0, 0, p); af1 = RD_A(1, 0, p);                              \
    af2 = RD_A(2, 0, p); af3 = RD_A(3, 0, p);                              \
    bw0 = RD_W(0, 0, p); bw1 = RD_W(1, 0, p);                              \
    bw2 = RD_W(2, 0, p); bw3 = RD_W(3, 0, p);                              \
    BARR; LGKM0; SCHB;                                                     \
    __builtin_amdgcn_s_setprio(1);                                         \
    MM(0, 0, af0, bw0); MM(1, 0, af1, bw0); MM(2, 0, af2, bw0); MM(3, 0, af3, bw0); \
    MM(0, 1, af0, bw1); MM(1, 1, af1, bw1); MM(2, 1, af2, bw1); MM(3, 1, af3, bw1); \
    MM(0, 2, af0, bw2); MM(1, 2, af1, bw2); MM(2, 2, af2, bw2); MM(3, 2, af3, bw2); \
    MM(0, 3, af0, bw3); MM(1, 3, af1, bw3); MM(2, 3, af2, bw3); MM(3, 3, af3, bw3); \
    __builtin_amdgcn_s_setprio(0);                                         \
    BARR;                                                                  \
    /* ---------------- phase B (kk=1) ---------------- */                 \
    if ((t) + 1 < nt) {                                                    \
        if ((t) + 2 < nt) { WAITV(6); } else { WAITV(0); }                 \
        SCHB;                                                              \
        WR_A(6, (p) ^ 1); WR_A(7, (p) ^ 1);                                \
        WR_W(0, (p) ^ 1); WR_W(1, (p) ^ 1); WR_W(2, (p) ^ 1); WR_W(3, (p) ^ 1); \
    }                                                                      \
    if ((t) + 2 < nt) {                                                    \
        ISS_A(6, k2_); ISS_A(7, k2_);                                      \
        ISS_W(0, k2_); ISS_W(1, k2_); ISS_W(2, k2_); ISS_W(3, k2_);        \
    }                                                                      \
    af0 = RD_A(0, 1, p); af1 = RD_A(1, 1, p);                              \
    af2 = RD_A(2, 1, p); af3 = RD_A(3, 1, p);                              \
    bw0 = RD_W(0, 1, p); bw1 = RD_W(1, 1, p);                              \
    bw2 = RD_W(2, 1, p); bw3 = RD_W(3, 1, p);                              \
    BARR; LGKM0; SCHB;                                                     \
    __builtin_amdgcn_s_setprio(1);                                         \
    MM(0, 0, af0, bw0); MM(1, 0, af1, bw0); MM(2, 0, af2, bw0); MM(3, 0, af3, bw0); \
    MM(0, 1, af0, bw1); MM(1, 1, af1, bw1); MM(2, 1, af2, bw1); MM(3, 1, af3, bw1); \
    MM(0, 2, af0, bw2); MM(1, 2, af1, bw2); MM(2, 2, af2, bw2); MM(3, 2, af3, bw2); \
    MM(0, 3, af0, bw3); MM(1, 3, af1, bw3); MM(2, 3, af2, bw3); MM(3, 3, af3, bw3); \
    __builtin_amdgcn_s_setprio(0);                                         \
    BARR;                                                                  \
} while (0)

    // prologue: tile 0 -> regs -> buf[0]; tile 1 loads in flight (issue
    // order A0..A7,W0..W3 matches the phases' retirement order).
    #pragma unroll
    for (int i = 0; i < 8; ++i) ISS_A(i, 0);
    #pragma unroll
    for (int j = 0; j < 4; ++j) ISS_W(j, 0);
    WAITV(0); SCHB;
    #pragma unroll
    for (int i = 0; i < 8; ++i) WR_A(i, 0);
    #pragma unroll
    for (int j = 0; j < 4; ++j) WR_W(j, 0);
    #pragma unroll
    for (int i = 0; i < 8; ++i) ISS_A(i, 64);
    #pragma unroll
    for (int j = 0; j < 4; ++j) ISS_W(j, 64);
    SCHB; LGKM0; BARR; SCHB;

    for (int t = 0; t + 1 < nt; t += 2) {    // pair-unroll: parity static
        STEP(t, 0);
        STEP(t + 1, 1);
    }
    if (nt & 1) STEP(nt - 1, 0);             // K-proj tail (nt=21)

#undef ISS_A
#undef ISS_W
#undef WR_A
#undef WR_W
#undef RD_A
#undef RD_W
#undef MM
#undef STEP

    // C/D layout: col = lane&15, row = (lane>>4)*4 + j  [m89-verified]
    const int r0 = (lane >> 4) * 4;
    #pragma unroll
    for (int n = 0; n < 4; ++n) {
        const int c = bcol + wc * 64 + n * 16 + fr;
        const float bv = bias[c];
        const float rv = isQ ? rb[c] : 0.0f;
        #pragma unroll
        for (int m = 0; m < 4; ++m) {
            const int row = brow + wr * 64 + m * 16 + r0;
            #pragma unroll
            for (int j = 0; j < 4; ++j) {
                float v = acc[m][n][j] + bv;
                if (isQ) v = 0.125f * v + rv;
                out[(size_t)(row + j) * 512 + c] = (__bf16)v;
            }
        }
    }
}

// ---------------------------------------------------------------------------
// Batched GEMM: out[b,i,j] = 0.125 * sum_c Q[b,i,c]*K[b,j,c]
// 128x128 tile, BK=64, gload_lds staging, swizzled bf16 LDS. (unchanged;
// ~9.6 us ~= its HBM floor: 33.5 MB write + 16 MB read)
// ---------------------------------------------------------------------------
__global__ __launch_bounds__(256, 2)
void attn_kernel(const __bf16* __restrict__ Q,
                 const __bf16* __restrict__ Kb,
                 float* __restrict__ out)
{
    __shared__ __bf16 As[128 * 64];   // 16 KB, linear dest (swizzled content)
    __shared__ __bf16 Bs[128 * 64];

    const int tid  = threadIdx.x;
    const int lane = tid & 63;
    const int wid  = tid >> 6;
    const int wr   = wid >> 1;
    const int wc   = wid & 1;
    const int b    = blockIdx.z;
    const int brow = blockIdx.y * 128;
    const int bcol = blockIdx.x * 128;

    const __bf16* Qb = Q  + (size_t)b * 1024 * 512;
    const __bf16* Kp = Kb + (size_t)b * 1024 * 512;

    const int fr = lane & 15;
    const int q4 = lane >> 4;

    f32x4 acc[4][4] = {};

    const int lr3 = lane >> 3;
    const int m3  = ((lr3 & 3) << 1) | ((lr3 >> 2) & 1);
    const int scol = ((lane & 7) ^ m3) * 8;            // swizzled global bf16 col
    const int rmask = ((fr & 3) << 1) | ((fr >> 2) & 1);

    for (int k0 = 0; k0 < 512; k0 += 64) {
        __syncthreads();
        #pragma unroll
        for (int i = 0; i < 4; ++i) {
            const int rbase = wid * 32 + i * 8;
            const __bf16* sa = Qb + (size_t)(brow + rbase + lr3) * 512 + k0 + scol;
            const __bf16* sb = Kp + (size_t)(bcol + rbase + lr3) * 512 + k0 + scol;
            __builtin_amdgcn_global_load_lds(
                (const __attribute__((address_space(1))) void*)sa,
                (__attribute__((address_space(3))) void*)&As[rbase * 64], 16, 0, 0);
            __builtin_amdgcn_global_load_lds(
                (const __attribute__((address_space(1))) void*)sb,
                (__attribute__((address_space(3))) void*)&Bs[rbase * 64], 16, 0, 0);
        }
        __syncthreads();

        #pragma unroll
        for (int kk = 0; kk < 2; ++kk) {
            const int ci = kk * 4 + q4;
            bf16x8 af[4], bf_[4];
            #pragma unroll
            for (int m = 0; m < 4; ++m)
                af[m] = *(const bf16x8*)(&As[(wr * 64 + m * 16 + fr) * 64 + ((ci ^ rmask) << 3)]);
            #pragma unroll
            for (int n = 0; n < 4; ++n)
                bf_[n] = *(const bf16x8*)(&Bs[(wc * 64 + n * 16 + fr) * 64 + ((ci ^ rmask) << 3)]);
            #pragma unroll
            for (int m = 0; m < 4; ++m)
                #pragma unroll
                for (int n = 0; n < 4; ++n)
                    acc[m][n] = __builtin_amdgcn_mfma_f32_16x16x32_bf16(af[m], bf_[n], acc[m][n], 0, 0, 0);
        }
    }

    float* op = out + (size_t)b * 1024 * 1024;
    const int r0 = (lane >> 4) * 4;
    #pragma unroll
    for (int n = 0; n < 4; ++n) {
        const int col = bcol + wc * 64 + n * 16 + fr;
        #pragma unroll
        for (int m = 0; m < 4; ++m) {
            const int row = brow + wr * 64 + m * 16 + r0;
            #pragma unroll
            for (int j = 0; j < 4; ++j)
                op[(size_t)(row + j) * 1024 + col] = 0.125f * acc[m][n][j];
        }
    }
}

extern "C" void kernel_launch(void* const* d_in, const int* in_sizes, int n_in,
                              void* d_out, int out_size, void* d_ws, size_t ws_size,
                              hipStream_t stream) {
    const float* rna  = (const float*)d_in[0];  // [8,1024,1280]
    const float* prot = (const float*)d_in[1];  // [8,1024,1344]
    const float* Wq   = (const float*)d_in[2];  // [512,1280]
    const float* bq   = (const float*)d_in[3];  // [512]
    const float* Wk   = (const float*)d_in[4];  // [512,1344]
    const float* bk   = (const float*)d_in[5];  // [512]
    const float* rb   = (const float*)d_in[6];  // [512] (flat idx == channel)

    __bf16* qws = (__bf16*)d_ws;                // [8192, 512] bf16 = 8 MB
    __bf16* kws = qws + (size_t)8192 * 512;     // [8192, 512] bf16 = 8 MB

    proj_all<<<dim3(256), dim3(512), 0, stream>>>(rna, prot, Wq, bq, Wk, bk, rb, qws, kws);
    attn_kernel<<<dim3(8, 8, 8), dim3(256), 0, stream>>>(qws, kws, (float*)d_out);
}